// Round 8
// baseline (214.153 us; speedup 1.0000x reference)
//
#include <hip/hip_runtime.h>
#include <math.h>

// ModulationIndex as i8 MFMA GEMM, v8: 512-block mi_main (2 blocks/CU) with
// last-block-of-pair fused epilogue (no second kernel).
// amp_sums[p*18+k, a] = sum_t onehot[pk, t] * amp[a, t]
// Grid 512 = (group bc*4+s, t-half); 512 thr; ~28KB LDS.
// amp quantized q = floor(amp*65536) u16 -> lo/hi i8 planes (bias -128);
// two mfma_i32_16x16x64_i8 per K=64 chunk; exact reconstruction:
// sum_q = 256*acc_h + acc_l + 32896*cnt (cnt from ones column in lo plane).
// Each block stores its half-table to ws slot; second finisher of the pair
// (agent-scope ticket) merges partner slot, computes entropy, atomicAdds out.

#define FP_ 10
#define FA_ 30
#define K_  18
#define T_  2048
#define TH_ 1024
#define TC_ 256
#define NTILE 4
#define NT_ 512

#define OFF_BINS 128
#define BINROW   1040                      // bytes per bins row (1024+16)
#define BSW_     260                       // words per bins row
#define OFF_LO   (OFF_BINS + FP_ * BINROW) // 10528
#define PROW     272                       // bytes per plane row (256+16)
#define PLSZ     (32 * PROW)               // 8704
#define OFF_HI   (OFF_LO + PLSZ)           // 19232
#define LDS_TOTAL (OFF_HI + PLSZ)          // 27936
#define OFF_RED  128                       // 192*33*4 = 25344 -> ends 25472
#define OFF_CNT  25472                     // +1536 = 27008 < 27936

#define SLOT_    6336                      // 192*33 f32 per half-table slot
#define CNT_OFF  (512 * SLOT_)             // f32 index of ticket counters in ws

typedef int i32x4 __attribute__((ext_vector_type(4)));

// 0x01 at bytes of w equal to replicated byte kb4 (zero-byte trick).
static __device__ __forceinline__ unsigned oh8(unsigned w, unsigned kb4) {
  const unsigned x = w ^ kb4;
  const unsigned t = (x & 0x7F7F7F7Fu) + 0x7F7F7F7Fu;
  return ((~(t | x)) & 0x80808080u) >> 7;
}

__global__ __launch_bounds__(NT_, 4)
void mi_main(const float* __restrict__ pha, const float* __restrict__ amp,
             float* __restrict__ ws, float* __restrict__ out) {
  extern __shared__ unsigned char smem[];
  __shared__ unsigned ticket_lds;
  float*    c_lds = (float*)smem;
  unsigned* binsw = (unsigned*)(smem + OFF_BINS);
  float*    red   = (float*)(smem + OFF_RED);
  int*      cnt_t = (int*)(smem + OFF_CNT);

  const int tid  = threadIdx.x;
  const int lane = tid & 63;
  const int wv   = tid >> 6;
  const int quad = lane >> 4;
  const int lc   = lane & 15;
  const int mq   = wv & 3;    // m-quarter: rows mq*48..+47
  const int q2   = wv >> 2;   // k-half

  const int bid  = blockIdx.x;
  const int g    = bid >> 1;  // bc*4 + s
  const int half = bid & 1;
  const int s    = g & 3;
  const int bc   = g >> 2;
  const long pha_base = (long)bc * (FP_ * 4L * T_) + (long)s * T_ + half * TH_;
  const long amp_base = (long)bc * (FA_ * 4L * T_) + (long)s * T_ + half * TH_;

  // cutoffs: bit-exact np.linspace(-pi, pi, 19) (f64 math, f32 cast)
  if (tid < 19) {
    const double PI_D = 3.14159265358979323846264338327950288;
    const double step = (2.0 * PI_D) / 18.0;
    c_lds[tid] = (tid == 18) ? (float)PI_D : (float)(-PI_D + (double)tid * step);
  }
  // static plane rows: 30 = ones in lo (counts, unbiased), zeros elsewhere
  if (tid < 17) {
    *(uint4*)(smem + OFF_LO + 30 * PROW + tid * 16) =
        make_uint4(0x01010101u, 0x01010101u, 0x01010101u, 0x01010101u);
    *(uint4*)(smem + OFF_LO + 31 * PROW + tid * 16) = make_uint4(0u, 0u, 0u, 0u);
    *(uint4*)(smem + OFF_HI + 30 * PROW + tid * 16) = make_uint4(0u, 0u, 0u, 0u);
    *(uint4*)(smem + OFF_HI + 31 * PROW + tid * 16) = make_uint4(0u, 0u, 0u, 0u);
  }

  // issue tile-0 amp loads first (latency hides under bins phase)
  const bool stager = tid < 480;
  const int a_row = tid >> 4;
  const int seg   = tid & 15;            // 16-t unit within tile
  const float* gsrc = amp + amp_base + (long)a_row * (4L * T_) + seg * 16;
  float4 vreg[4];
  if (stager) {
    #pragma unroll
    for (int j = 0; j < 4; ++j) vreg[j] = *(const float4*)(gsrc + j * 4);
  }

  // --- bins: 2560 u32 words (u8 bins, 4 t each)
  const float PI_F    = 3.14159274101257324f;
  const float INVSTEP = 2.8647890f;
  #pragma unroll
  for (int it = 0; it < 5; ++it) {
    const int i = it * NT_ + tid;
    const int p = i >> 8, w = i & 255;
    const float4 v = *(const float4*)(pha + pha_base + (long)p * (4L * T_) + w * 4);
    const float xs[4] = {v.x, v.y, v.z, v.w};
    unsigned pk = 0;
    #pragma unroll
    for (int j = 0; j < 4; ++j) {
      const float x = xs[j];
      int gi = (int)((x + PI_F) * INVSTEP);
      gi = min(17, max(0, gi));
      if (x <= c_lds[gi]) gi -= 1;        // searchsorted-left: c_b < x <= c_{b+1}
      else if (x > c_lds[gi + 1]) gi += 1;
      gi = min(17, max(0, gi));
      pk |= ((unsigned)gi) << (8 * j);
    }
    binsw[p * BSW_ + w] = pk;
  }

  // per-wave A-row tables (A operand: m = lane&15)
  int p_mt[3]; unsigned kb4_mt[3];
  #pragma unroll
  for (int mt = 0; mt < 3; ++mt) {
    const int row = mq * 48 + mt * 16 + lc;
    int p = row / 18; p = min(p, 9);
    const unsigned kb = (unsigned)(row - p * 18);   // >=18 on pad rows
    p_mt[mt] = p;
    kb4_mt[mt] = kb * 0x01010101u;
  }

  i32x4 accl[3][2], acch[3][2];
  #pragma unroll
  for (int mt = 0; mt < 3; ++mt) {
    accl[mt][0] = (i32x4){0,0,0,0}; accl[mt][1] = (i32x4){0,0,0,0};
    acch[mt][0] = (i32x4){0,0,0,0}; acch[mt][1] = (i32x4){0,0,0,0};
  }
  __syncthreads();   // bins + cutoffs + const rows visible

  #pragma unroll 1
  for (int tile = 0; tile < NTILE; ++tile) {
    if (stager) {   // quantize + byte-split + write 16 t into both planes
      unsigned lo[4], hi[4];
      #pragma unroll
      for (int j = 0; j < 4; ++j) {
        const float xv[4] = {vreg[j].x, vreg[j].y, vreg[j].z, vreg[j].w};
        unsigned q[4];
        #pragma unroll
        for (int e = 0; e < 4; ++e)
          q[e] = min((unsigned)(xv[e] * 65536.0f), 65535u);
        const unsigned w01 = q[0] | (q[1] << 16);
        const unsigned w23 = q[2] | (q[3] << 16);
        lo[j] = __builtin_amdgcn_perm(w23, w01, 0x06040200u) ^ 0x80808080u;
        hi[j] = __builtin_amdgcn_perm(w23, w01, 0x07050301u) ^ 0x80808080u;
      }
      *(uint4*)(smem + OFF_LO + a_row * PROW + seg * 16) = make_uint4(lo[0], lo[1], lo[2], lo[3]);
      *(uint4*)(smem + OFF_HI + a_row * PROW + seg * 16) = make_uint4(hi[0], hi[1], hi[2], hi[3]);
    }
    __syncthreads();
    if (stager && tile < NTILE - 1) {   // prefetch next tile during compute
      #pragma unroll
      for (int j = 0; j < 4; ++j)
        vreg[j] = *(const float4*)(gsrc + (tile + 1) * TC_ + j * 4);
    }

    #pragma unroll
    for (int ci = 0; ci < 2; ++ci) {
      const int cl = q2 * 2 + ci;                 // 64-t chunk 0..3 in tile
      const unsigned char* bl = smem + OFF_LO + cl * 64 + quad * 16;
      const unsigned char* bh = smem + OFF_HI + cl * 64 + quad * 16;
      const i32x4 Bl0 = *(const i32x4*)(bl + lc * PROW);
      const i32x4 Bl1 = *(const i32x4*)(bl + (16 + lc) * PROW);
      const i32x4 Bh0 = *(const i32x4*)(bh + lc * PROW);
      const i32x4 Bh1 = *(const i32x4*)(bh + (16 + lc) * PROW);
      const int chg = tile * 4 + cl;              // global 64-t chunk 0..15
      #pragma unroll
      for (int mt = 0; mt < 3; ++mt) {
        const uint4 wb = *(const uint4*)(smem + OFF_BINS + p_mt[mt] * BINROW
                                         + chg * 64 + quad * 16);
        const unsigned kb4 = kb4_mt[mt];
        const i32x4 A = (i32x4){(int)oh8(wb.x, kb4), (int)oh8(wb.y, kb4),
                                (int)oh8(wb.z, kb4), (int)oh8(wb.w, kb4)};
        accl[mt][0] = __builtin_amdgcn_mfma_i32_16x16x64_i8(A, Bl0, accl[mt][0], 0, 0, 0);
        acch[mt][0] = __builtin_amdgcn_mfma_i32_16x16x64_i8(A, Bh0, acch[mt][0], 0, 0, 0);
        accl[mt][1] = __builtin_amdgcn_mfma_i32_16x16x64_i8(A, Bl1, accl[mt][1], 0, 0, 0);
        acch[mt][1] = __builtin_amdgcn_mfma_i32_16x16x64_i8(A, Bh1, acch[mt][1], 0, 0, 0);
      }
    }
    __syncthreads();   // reads done before next tile's staging overwrite
  }

  // --- per-half counts table (col 30 = n=1, lc=14); C layout: row=quad*4+r
  if (lc == 14) {
    #pragma unroll
    for (int mt = 0; mt < 3; ++mt)
      #pragma unroll
      for (int r = 0; r < 4; ++r)
        cnt_t[q2 * 192 + mq * 48 + mt * 16 + quad * 4 + r] = accl[mt][1][r];
  }
  __syncthreads();

  // exact reconstruction to f32 per-half sums
  float vals[3][2][4];
  #pragma unroll
  for (int mt = 0; mt < 3; ++mt)
    #pragma unroll
    for (int n = 0; n < 2; ++n)
      #pragma unroll
      for (int r = 0; r < 4; ++r) {
        const int row = mq * 48 + mt * 16 + quad * 4 + r;
        const int cnt = cnt_t[q2 * 192 + row];
        const int raw = (acch[mt][n][r] << 8) + accl[mt][n][r] + 32896 * cnt;
        float v = (float)raw * 1.52587890625e-5f;   // / 65536
        if (n == 1 && lc == 14) v = (float)accl[mt][n][r];   // counts column raw
        vals[mt][n][r] = v;
      }
  __syncthreads();

  // k-half combine in red: q2==1 stores, q2==0 adds back -> red holds half-total
  if (q2 == 1) {
    float* S = &red[mq * 48 * 33];
    #pragma unroll
    for (int mt = 0; mt < 3; ++mt)
      #pragma unroll
      for (int n = 0; n < 2; ++n)
        #pragma unroll
        for (int r = 0; r < 4; ++r)
          S[(mt * 16 + quad * 4 + r) * 33 + n * 16 + lc] = vals[mt][n][r];
  }
  __syncthreads();
  if (q2 == 0) {
    float* S = &red[mq * 48 * 33];
    #pragma unroll
    for (int mt = 0; mt < 3; ++mt)
      #pragma unroll
      for (int n = 0; n < 2; ++n)
        #pragma unroll
        for (int r = 0; r < 4; ++r) {
          const int idx = (mt * 16 + quad * 4 + r) * 33 + n * 16 + lc;
          S[idx] = vals[mt][n][r] + S[idx];
        }
  }
  __syncthreads();

  // --- store half-table slot (plain coalesced stores), then ticket.
  float* slot = ws + (long)bid * SLOT_;
  #pragma unroll
  for (int it = 0; it < 13; ++it) {
    const int i = it * NT_ + tid;
    if (i < SLOT_) slot[i] = red[i];
  }
  __syncthreads();   // drains vmcnt: all stores complete before ticket
  if (tid == 0) {
    __threadfence();   // agent release: slot visible device-wide
    unsigned* cnt = (unsigned*)(ws + CNT_OFF);
    ticket_lds = __hip_atomic_fetch_add(&cnt[g], 1u, __ATOMIC_ACQ_REL,
                                        __HIP_MEMORY_SCOPE_AGENT);
  }
  __syncthreads();
  if (ticket_lds == 0) return;   // first finisher of the pair exits

  // --- winner: merge partner slot, entropy, atomicAdd into out.
  __threadfence();   // agent acquire: invalidate stale cache lines
  const float* partner = ws + (long)(bid ^ 1) * SLOT_;
  #pragma unroll
  for (int it = 0; it < 13; ++it) {
    const int i = it * NT_ + tid;
    if (i < SLOT_) red[i] += partner[i];
  }
  __syncthreads();

  if (tid < FP_ * FA_) {
    const int p = tid / FA_;
    const int a = tid - p * FA_;
    float m[K_];
    float tot = 0.0f;
    #pragma unroll
    for (int k = 0; k < K_; ++k) {
      const float cnt = red[(p * K_ + k) * 33 + 30];
      const float sv  = red[(p * K_ + k) * 33 + a];
      const float mk  = sv / (cnt + 1e-9f);
      m[k] = mk;
      tot += mk;
    }
    const float denom = tot + 1e-9f;
    float ent = 0.0f;
    #pragma unroll
    for (int k = 0; k < K_; ++k) {
      const float pr = m[k] / denom;
      ent += pr * logf(pr + 1e-9f);
    }
    const float L  = logf(18.0f);
    const float mi = (L + ent) / L;
    atomicAdd(&out[(bc * FP_ + p) * FA_ + a], 0.25f * mi);
  }
}

extern "C" void kernel_launch(void* const* d_in, const int* in_sizes, int n_in,
                              void* d_out, int out_size, void* d_ws, size_t ws_size,
                              hipStream_t stream) {
  const float* pha = (const float*)d_in[0];
  const float* amp = (const float*)d_in[1];
  float* out = (float*)d_out;
  float* ws  = (float*)d_ws;   // slots 13.0 MB + 1 KB tickets

  hipMemsetAsync(d_out, 0, (size_t)out_size * sizeof(float), stream);
  hipMemsetAsync((char*)d_ws + (size_t)CNT_OFF * 4, 0, 256 * 4, stream);
  hipLaunchKernelGGL(mi_main, dim3(512), dim3(NT_), LDS_TOTAL, stream,
                     pha, amp, ws, out);
}

// Round 9
// 117.814 us; speedup vs baseline: 1.8177x; 1.8177x over previous
//
#include <hip/hip_runtime.h>
#include <math.h>

// ModulationIndex as i8 MFMA GEMM, v9: R6 structure, T quartered for
// 4 blocks/CU co-residency (32 waves/CU), no device-scope fences.
// amp_sums[p*18+k, a] = sum_t onehot[pk, t] * amp[a, t]
// Grid 1024 = (group bc*4+s, t-quarter); 512 thr; ~27KB LDS.
// amp quantized q = floor(amp*65536) u16 -> lo/hi i8 planes (bias -128);
// two mfma_i32_16x16x64_i8 per K=64 chunk; exact reconstruction:
// sum_q = 256*acc_h + acc_l + 32896*cnt (cnt from ones column in lo plane).
// f32 partial tables -> ws; mi_ent merges 16 quarters, entropy, s-mean.

#define FP_ 10
#define FA_ 30
#define K_  18
#define T_  2048
#define TQ_ 512
#define TC_ 256
#define NTILE 2
#define NT_ 512

#define OFF_BINS 128
#define BINROW   528                       // bytes per bins row (512+16)
#define BSW_     132                       // words per bins row
#define OFF_LO   (OFF_BINS + FP_ * BINROW) // 5408
#define PROW     272                       // bytes per plane row (256+16)
#define PLSZ     (32 * PROW)               // 8704
#define OFF_HI   (OFF_LO + PLSZ)           // 14112
#define OFF_RED  128                       // 192*33*4 = 25344 -> ends 25472
#define OFF_CNT  25472                     // +1536 = 27008
#define LDS_TOTAL 27008                    // x4 blocks = 108 KB < 160 KB

typedef int i32x4 __attribute__((ext_vector_type(4)));

// 0x01 at bytes of w equal to replicated byte kb4 (zero-byte trick).
static __device__ __forceinline__ unsigned oh8(unsigned w, unsigned kb4) {
  const unsigned x = w ^ kb4;
  const unsigned t = (x & 0x7F7F7F7Fu) + 0x7F7F7F7Fu;
  return ((~(t | x)) & 0x80808080u) >> 7;
}

__global__ __launch_bounds__(NT_, 4)
void mi_main(const float* __restrict__ pha, const float* __restrict__ amp,
             float* __restrict__ ws) {
  extern __shared__ unsigned char smem[];
  float*    c_lds = (float*)smem;
  unsigned* binsw = (unsigned*)(smem + OFF_BINS);
  float*    red   = (float*)(smem + OFF_RED);
  int*      cnt_t = (int*)(smem + OFF_CNT);

  const int tid  = threadIdx.x;
  const int lane = tid & 63;
  const int wv   = tid >> 6;
  const int quad = lane >> 4;
  const int lc   = lane & 15;
  const int mq   = wv & 3;    // m-quarter: rows mq*48..+47
  const int q2   = wv >> 2;   // k-half

  const int bid = blockIdx.x;
  const int g   = bid >> 2;   // bc*4 + s
  const int qt  = bid & 3;    // t-quarter
  const int s   = g & 3;
  const int bc  = g >> 2;
  const long pha_base = (long)bc * (FP_ * 4L * T_) + (long)s * T_ + qt * TQ_;
  const long amp_base = (long)bc * (FA_ * 4L * T_) + (long)s * T_ + qt * TQ_;

  // cutoffs: bit-exact np.linspace(-pi, pi, 19) (f64 math, f32 cast)
  if (tid < 19) {
    const double PI_D = 3.14159265358979323846264338327950288;
    const double step = (2.0 * PI_D) / 18.0;
    c_lds[tid] = (tid == 18) ? (float)PI_D : (float)(-PI_D + (double)tid * step);
  }
  // static plane rows: 30 = ones in lo (counts, unbiased), zeros elsewhere
  if (tid < 17) {
    *(uint4*)(smem + OFF_LO + 30 * PROW + tid * 16) =
        make_uint4(0x01010101u, 0x01010101u, 0x01010101u, 0x01010101u);
    *(uint4*)(smem + OFF_LO + 31 * PROW + tid * 16) = make_uint4(0u, 0u, 0u, 0u);
    *(uint4*)(smem + OFF_HI + 30 * PROW + tid * 16) = make_uint4(0u, 0u, 0u, 0u);
    *(uint4*)(smem + OFF_HI + 31 * PROW + tid * 16) = make_uint4(0u, 0u, 0u, 0u);
  }

  // issue tile-0 amp loads first (latency hides under bins phase)
  const bool stager = tid < 480;
  const int a_row = tid >> 4;
  const int seg   = tid & 15;            // 16-t unit within tile
  const float* gsrc = amp + amp_base + (long)a_row * (4L * T_) + seg * 16;
  float4 vreg[4];
  if (stager) {
    #pragma unroll
    for (int j = 0; j < 4; ++j) vreg[j] = *(const float4*)(gsrc + j * 4);
  }

  // --- bins: 1280 u32 words (u8 bins, 4 t each)
  const float PI_F    = 3.14159274101257324f;
  const float INVSTEP = 2.8647890f;
  #pragma unroll
  for (int it = 0; it < 3; ++it) {
    const int i = it * NT_ + tid;
    if (i < 1280) {
      const int p = i >> 7, w = i & 127;
      const float4 v = *(const float4*)(pha + pha_base + (long)p * (4L * T_) + w * 4);
      const float xs[4] = {v.x, v.y, v.z, v.w};
      unsigned pk = 0;
      #pragma unroll
      for (int j = 0; j < 4; ++j) {
        const float x = xs[j];
        int gi = (int)((x + PI_F) * INVSTEP);
        gi = min(17, max(0, gi));
        if (x <= c_lds[gi]) gi -= 1;      // searchsorted-left: c_b < x <= c_{b+1}
        else if (x > c_lds[gi + 1]) gi += 1;
        gi = min(17, max(0, gi));
        pk |= ((unsigned)gi) << (8 * j);
      }
      binsw[p * BSW_ + w] = pk;
    }
  }

  // per-wave A-row tables (A operand: m = lane&15)
  int p_mt[3]; unsigned kb4_mt[3];
  #pragma unroll
  for (int mt = 0; mt < 3; ++mt) {
    const int row = mq * 48 + mt * 16 + lc;
    int p = row / 18; p = min(p, 9);
    const unsigned kb = (unsigned)(row - p * 18);   // >=18 on pad rows
    p_mt[mt] = p;
    kb4_mt[mt] = kb * 0x01010101u;
  }

  i32x4 accl[3][2], acch[3][2];
  #pragma unroll
  for (int mt = 0; mt < 3; ++mt) {
    accl[mt][0] = (i32x4){0,0,0,0}; accl[mt][1] = (i32x4){0,0,0,0};
    acch[mt][0] = (i32x4){0,0,0,0}; acch[mt][1] = (i32x4){0,0,0,0};
  }
  __syncthreads();   // bins + cutoffs + const rows visible

  #pragma unroll 1
  for (int tile = 0; tile < NTILE; ++tile) {
    if (stager) {   // quantize + byte-split + write 16 t into both planes
      unsigned lo[4], hi[4];
      #pragma unroll
      for (int j = 0; j < 4; ++j) {
        const float xv[4] = {vreg[j].x, vreg[j].y, vreg[j].z, vreg[j].w};
        unsigned q[4];
        #pragma unroll
        for (int e = 0; e < 4; ++e)
          q[e] = min((unsigned)(xv[e] * 65536.0f), 65535u);
        const unsigned w01 = q[0] | (q[1] << 16);
        const unsigned w23 = q[2] | (q[3] << 16);
        lo[j] = __builtin_amdgcn_perm(w23, w01, 0x06040200u) ^ 0x80808080u;
        hi[j] = __builtin_amdgcn_perm(w23, w01, 0x07050301u) ^ 0x80808080u;
      }
      *(uint4*)(smem + OFF_LO + a_row * PROW + seg * 16) = make_uint4(lo[0], lo[1], lo[2], lo[3]);
      *(uint4*)(smem + OFF_HI + a_row * PROW + seg * 16) = make_uint4(hi[0], hi[1], hi[2], hi[3]);
    }
    __syncthreads();
    if (stager && tile < NTILE - 1) {   // prefetch next tile during compute
      #pragma unroll
      for (int j = 0; j < 4; ++j)
        vreg[j] = *(const float4*)(gsrc + (tile + 1) * TC_ + j * 4);
    }

    #pragma unroll
    for (int ci = 0; ci < 2; ++ci) {
      const int cl = q2 * 2 + ci;                 // 64-t chunk 0..3 in tile
      const unsigned char* bl = smem + OFF_LO + cl * 64 + quad * 16;
      const unsigned char* bh = smem + OFF_HI + cl * 64 + quad * 16;
      const i32x4 Bl0 = *(const i32x4*)(bl + lc * PROW);
      const i32x4 Bl1 = *(const i32x4*)(bl + (16 + lc) * PROW);
      const i32x4 Bh0 = *(const i32x4*)(bh + lc * PROW);
      const i32x4 Bh1 = *(const i32x4*)(bh + (16 + lc) * PROW);
      const int chg = tile * 4 + cl;              // global 64-t chunk 0..7
      #pragma unroll
      for (int mt = 0; mt < 3; ++mt) {
        const uint4 wb = *(const uint4*)(smem + OFF_BINS + p_mt[mt] * BINROW
                                         + chg * 64 + quad * 16);
        const unsigned kb4 = kb4_mt[mt];
        const i32x4 A = (i32x4){(int)oh8(wb.x, kb4), (int)oh8(wb.y, kb4),
                                (int)oh8(wb.z, kb4), (int)oh8(wb.w, kb4)};
        accl[mt][0] = __builtin_amdgcn_mfma_i32_16x16x64_i8(A, Bl0, accl[mt][0], 0, 0, 0);
        acch[mt][0] = __builtin_amdgcn_mfma_i32_16x16x64_i8(A, Bh0, acch[mt][0], 0, 0, 0);
        accl[mt][1] = __builtin_amdgcn_mfma_i32_16x16x64_i8(A, Bl1, accl[mt][1], 0, 0, 0);
        acch[mt][1] = __builtin_amdgcn_mfma_i32_16x16x64_i8(A, Bh1, acch[mt][1], 0, 0, 0);
      }
    }
    __syncthreads();   // reads done before next tile's staging overwrite
  }

  // --- per-half counts table (col 30 = n=1, lc=14); C layout: row=quad*4+r
  if (lc == 14) {
    #pragma unroll
    for (int mt = 0; mt < 3; ++mt)
      #pragma unroll
      for (int r = 0; r < 4; ++r)
        cnt_t[q2 * 192 + mq * 48 + mt * 16 + quad * 4 + r] = accl[mt][1][r];
  }
  __syncthreads();

  // exact reconstruction to f32 per-half sums
  float vals[3][2][4];
  #pragma unroll
  for (int mt = 0; mt < 3; ++mt)
    #pragma unroll
    for (int n = 0; n < 2; ++n)
      #pragma unroll
      for (int r = 0; r < 4; ++r) {
        const int row = mq * 48 + mt * 16 + quad * 4 + r;
        const int cnt = cnt_t[q2 * 192 + row];
        const int raw = (acch[mt][n][r] << 8) + accl[mt][n][r] + 32896 * cnt;
        float v = (float)raw * 1.52587890625e-5f;   // / 65536
        if (n == 1 && lc == 14) v = (float)accl[mt][n][r];   // counts column raw
        vals[mt][n][r] = v;
      }
  __syncthreads();

  // k-half combine: q2==1 stores to red, q2==0 adds and writes ws
  if (q2 == 1) {
    float* S = &red[mq * 48 * 33];
    #pragma unroll
    for (int mt = 0; mt < 3; ++mt)
      #pragma unroll
      for (int n = 0; n < 2; ++n)
        #pragma unroll
        for (int r = 0; r < 4; ++r)
          S[(mt * 16 + quad * 4 + r) * 33 + n * 16 + lc] = vals[mt][n][r];
  }
  __syncthreads();
  if (q2 == 0) {
    float* S = &red[mq * 48 * 33];
    float* W = ws + (long)bid * 6144;
    #pragma unroll
    for (int mt = 0; mt < 3; ++mt)
      #pragma unroll
      for (int n = 0; n < 2; ++n)
        #pragma unroll
        for (int r = 0; r < 4; ++r) {
          const float v = vals[mt][n][r] + S[(mt * 16 + quad * 4 + r) * 33 + n * 16 + lc];
          W[(mq * 48 + mt * 16 + quad * 4 + r) * 32 + n * 16 + lc] = v;
        }
  }
}

// Epilogue: one block per (bc, p). Stage 16x576 partials coalesced into LDS,
// 120 threads (s,a) compute entropy, 30 threads reduce over s.
__global__ __launch_bounds__(256)
void mi_ent(const float* __restrict__ ws, float* __restrict__ out) {
  __shared__ float tbl[16 * 576];
  __shared__ float red[4][32];
  const int bc = blockIdx.x / FP_;
  const int p  = blockIdx.x - bc * FP_;
  const int tid = threadIdx.x;

  #pragma unroll
  for (int it = 0; it < 36; ++it) {
    const int i = it * 256 + tid;
    const int sub = i / 576, r = i - sub * 576;   // sub = s*4 + qt
    tbl[i] = ws[(long)(bc * 16 + sub) * 6144 + p * 576 + r];
  }
  __syncthreads();

  if (tid < 120) {
    const int s = tid / FA_;
    const int a = tid - s * FA_;
    const float* t0 = &tbl[(s * 4 + 0) * 576];
    const float* t1 = &tbl[(s * 4 + 1) * 576];
    const float* t2 = &tbl[(s * 4 + 2) * 576];
    const float* t3 = &tbl[(s * 4 + 3) * 576];
    float m[K_];
    float tot = 0.0f;
    #pragma unroll
    for (int k = 0; k < K_; ++k) {
      const float cnt = (t0[k*32+30] + t1[k*32+30]) + (t2[k*32+30] + t3[k*32+30]);
      const float sv  = (t0[k*32+a]  + t1[k*32+a])  + (t2[k*32+a]  + t3[k*32+a]);
      const float mk  = sv / (cnt + 1e-9f);
      m[k] = mk;
      tot += mk;
    }
    const float denom = tot + 1e-9f;
    float ent = 0.0f;
    #pragma unroll
    for (int k = 0; k < K_; ++k) {
      const float pr = m[k] / denom;
      ent += pr * logf(pr + 1e-9f);
    }
    const float L = logf(18.0f);
    red[s][a] = (L + ent) / L;
  }
  __syncthreads();
  if (tid < FA_)
    out[(bc * FP_ + p) * FA_ + tid] =
        0.25f * (red[0][tid] + red[1][tid] + red[2][tid] + red[3][tid]);
}

extern "C" void kernel_launch(void* const* d_in, const int* in_sizes, int n_in,
                              void* d_out, int out_size, void* d_ws, size_t ws_size,
                              hipStream_t stream) {
  const float* pha = (const float*)d_in[0];
  const float* amp = (const float*)d_in[1];
  float* out = (float*)d_out;
  float* ws  = (float*)d_ws;   // 1024 * 6144 f32 = 25.2 MB partials

  hipLaunchKernelGGL(mi_main, dim3(1024), dim3(NT_), LDS_TOTAL, stream, pha, amp, ws);
  hipLaunchKernelGGL(mi_ent, dim3(64 * FP_), dim3(256), 0, stream, ws, out);
}

// Round 10
// 113.221 us; speedup vs baseline: 1.8915x; 1.0406x over previous
//
#include <hip/hip_runtime.h>
#include <math.h>

// ModulationIndex as i8 MFMA GEMM, v10 = R6 (best: 112.2us) with the
// post-K-loop tail shortened: counts broadcast via __shfl from the wave's
// own counts column (C col 30 = lane quad*16+14) instead of an LDS table.
// Removes 2 barriers + cnt_t round-trip per block.
// amp_sums[p*18+k, a] = sum_t onehot[pk, t] * amp[a, t]
// Grid 512 = (group bc*4+s, t-half); 512 thr; 2 blocks/CU.
// amp quantized q = floor(amp*65536) u16 -> lo/hi i8 planes (bias -128);
// two mfma_i32_16x16x64_i8 per K=64 chunk; exact reconstruction:
// sum_q = 256*acc_h + acc_l + 32896*cnt (cnt from ones column in lo plane).
// f32 half-tables -> ws; mi_ent merges 8 slots, entropy, s-mean.

#define FP_ 10
#define FA_ 30
#define K_  18
#define T_  2048
#define TH_ 1024
#define TC_ 256
#define NTILE 4
#define NT_ 512

#define OFF_BINS 128
#define BINROW   1040                      // bytes per bins row (1024+16)
#define BSW_     260                       // words per bins row
#define OFF_LO   (OFF_BINS + FP_ * BINROW) // 10528
#define PROW     272                       // bytes per plane row (256+16)
#define PLSZ     (32 * PROW)               // 8704
#define OFF_HI   (OFF_LO + PLSZ)           // 19232
#define LDS_TOTAL (OFF_HI + PLSZ)          // 27936
#define OFF_RED  128                       // 192*33*4 = 25344 -> ends 25472

typedef int i32x4 __attribute__((ext_vector_type(4)));

// 0x01 at bytes of w equal to replicated byte kb4 (zero-byte trick).
static __device__ __forceinline__ unsigned oh8(unsigned w, unsigned kb4) {
  const unsigned x = w ^ kb4;
  const unsigned t = (x & 0x7F7F7F7Fu) + 0x7F7F7F7Fu;
  return ((~(t | x)) & 0x80808080u) >> 7;
}

__global__ __launch_bounds__(NT_, 4)
void mi_main(const float* __restrict__ pha, const float* __restrict__ amp,
             float* __restrict__ ws) {
  extern __shared__ unsigned char smem[];
  float*    c_lds = (float*)smem;
  unsigned* binsw = (unsigned*)(smem + OFF_BINS);
  float*    red   = (float*)(smem + OFF_RED);

  const int tid  = threadIdx.x;
  const int lane = tid & 63;
  const int wv   = tid >> 6;
  const int quad = lane >> 4;
  const int lc   = lane & 15;
  const int mq   = wv & 3;    // m-quarter: rows mq*48..+47
  const int q2   = wv >> 2;   // k-half

  const int bid  = blockIdx.x;
  const int g    = bid >> 1;  // bc*4 + s
  const int half = bid & 1;
  const int s    = g & 3;
  const int bc   = g >> 2;
  const long pha_base = (long)bc * (FP_ * 4L * T_) + (long)s * T_ + half * TH_;
  const long amp_base = (long)bc * (FA_ * 4L * T_) + (long)s * T_ + half * TH_;

  // cutoffs: bit-exact np.linspace(-pi, pi, 19) (f64 math, f32 cast)
  if (tid < 19) {
    const double PI_D = 3.14159265358979323846264338327950288;
    const double step = (2.0 * PI_D) / 18.0;
    c_lds[tid] = (tid == 18) ? (float)PI_D : (float)(-PI_D + (double)tid * step);
  }
  // static plane rows: 30 = ones in lo (counts, unbiased), zeros elsewhere
  if (tid < 17) {
    *(uint4*)(smem + OFF_LO + 30 * PROW + tid * 16) =
        make_uint4(0x01010101u, 0x01010101u, 0x01010101u, 0x01010101u);
    *(uint4*)(smem + OFF_LO + 31 * PROW + tid * 16) = make_uint4(0u, 0u, 0u, 0u);
    *(uint4*)(smem + OFF_HI + 30 * PROW + tid * 16) = make_uint4(0u, 0u, 0u, 0u);
    *(uint4*)(smem + OFF_HI + 31 * PROW + tid * 16) = make_uint4(0u, 0u, 0u, 0u);
  }

  // issue tile-0 amp loads first (latency hides under bins phase)
  const bool stager = tid < 480;
  const int a_row = tid >> 4;
  const int seg   = tid & 15;            // 16-t unit within tile
  const float* gsrc = amp + amp_base + (long)a_row * (4L * T_) + seg * 16;
  float4 vreg[4];
  if (stager) {
    #pragma unroll
    for (int j = 0; j < 4; ++j) vreg[j] = *(const float4*)(gsrc + j * 4);
  }

  // --- bins: 2560 u32 words (u8 bins, 4 t each)
  const float PI_F    = 3.14159274101257324f;
  const float INVSTEP = 2.8647890f;
  #pragma unroll
  for (int it = 0; it < 5; ++it) {
    const int i = it * NT_ + tid;
    const int p = i >> 8, w = i & 255;
    const float4 v = *(const float4*)(pha + pha_base + (long)p * (4L * T_) + w * 4);
    const float xs[4] = {v.x, v.y, v.z, v.w};
    unsigned pk = 0;
    #pragma unroll
    for (int j = 0; j < 4; ++j) {
      const float x = xs[j];
      int gi = (int)((x + PI_F) * INVSTEP);
      gi = min(17, max(0, gi));
      if (x <= c_lds[gi]) gi -= 1;        // searchsorted-left: c_b < x <= c_{b+1}
      else if (x > c_lds[gi + 1]) gi += 1;
      gi = min(17, max(0, gi));
      pk |= ((unsigned)gi) << (8 * j);
    }
    binsw[p * BSW_ + w] = pk;
  }

  // per-wave A-row tables (A operand: m = lane&15)
  int p_mt[3]; unsigned kb4_mt[3];
  #pragma unroll
  for (int mt = 0; mt < 3; ++mt) {
    const int row = mq * 48 + mt * 16 + lc;
    int p = row / 18; p = min(p, 9);
    const unsigned kb = (unsigned)(row - p * 18);   // >=18 on pad rows
    p_mt[mt] = p;
    kb4_mt[mt] = kb * 0x01010101u;
  }

  i32x4 accl[3][2], acch[3][2];
  #pragma unroll
  for (int mt = 0; mt < 3; ++mt) {
    accl[mt][0] = (i32x4){0,0,0,0}; accl[mt][1] = (i32x4){0,0,0,0};
    acch[mt][0] = (i32x4){0,0,0,0}; acch[mt][1] = (i32x4){0,0,0,0};
  }
  __syncthreads();   // bins + cutoffs + const rows visible

  #pragma unroll 1
  for (int tile = 0; tile < NTILE; ++tile) {
    if (stager) {   // quantize + byte-split + write 16 t into both planes
      unsigned lo[4], hi[4];
      #pragma unroll
      for (int j = 0; j < 4; ++j) {
        const float xv[4] = {vreg[j].x, vreg[j].y, vreg[j].z, vreg[j].w};
        unsigned q[4];
        #pragma unroll
        for (int e = 0; e < 4; ++e)
          q[e] = min((unsigned)(xv[e] * 65536.0f), 65535u);
        const unsigned w01 = q[0] | (q[1] << 16);
        const unsigned w23 = q[2] | (q[3] << 16);
        lo[j] = __builtin_amdgcn_perm(w23, w01, 0x06040200u) ^ 0x80808080u;
        hi[j] = __builtin_amdgcn_perm(w23, w01, 0x07050301u) ^ 0x80808080u;
      }
      *(uint4*)(smem + OFF_LO + a_row * PROW + seg * 16) = make_uint4(lo[0], lo[1], lo[2], lo[3]);
      *(uint4*)(smem + OFF_HI + a_row * PROW + seg * 16) = make_uint4(hi[0], hi[1], hi[2], hi[3]);
    }
    __syncthreads();
    if (stager && tile < NTILE - 1) {   // prefetch next tile during compute
      #pragma unroll
      for (int j = 0; j < 4; ++j)
        vreg[j] = *(const float4*)(gsrc + (tile + 1) * TC_ + j * 4);
    }

    #pragma unroll
    for (int ci = 0; ci < 2; ++ci) {
      const int cl = q2 * 2 + ci;                 // 64-t chunk 0..3 in tile
      const unsigned char* bl = smem + OFF_LO + cl * 64 + quad * 16;
      const unsigned char* bh = smem + OFF_HI + cl * 64 + quad * 16;
      const i32x4 Bl0 = *(const i32x4*)(bl + lc * PROW);
      const i32x4 Bl1 = *(const i32x4*)(bl + (16 + lc) * PROW);
      const i32x4 Bh0 = *(const i32x4*)(bh + lc * PROW);
      const i32x4 Bh1 = *(const i32x4*)(bh + (16 + lc) * PROW);
      const int chg = tile * 4 + cl;              // global 64-t chunk 0..15
      #pragma unroll
      for (int mt = 0; mt < 3; ++mt) {
        const uint4 wb = *(const uint4*)(smem + OFF_BINS + p_mt[mt] * BINROW
                                         + chg * 64 + quad * 16);
        const unsigned kb4 = kb4_mt[mt];
        const i32x4 A = (i32x4){(int)oh8(wb.x, kb4), (int)oh8(wb.y, kb4),
                                (int)oh8(wb.z, kb4), (int)oh8(wb.w, kb4)};
        accl[mt][0] = __builtin_amdgcn_mfma_i32_16x16x64_i8(A, Bl0, accl[mt][0], 0, 0, 0);
        acch[mt][0] = __builtin_amdgcn_mfma_i32_16x16x64_i8(A, Bh0, acch[mt][0], 0, 0, 0);
        accl[mt][1] = __builtin_amdgcn_mfma_i32_16x16x64_i8(A, Bl1, accl[mt][1], 0, 0, 0);
        acch[mt][1] = __builtin_amdgcn_mfma_i32_16x16x64_i8(A, Bh1, acch[mt][1], 0, 0, 0);
      }
    }
    __syncthreads();   // reads done before next tile's staging overwrite
  }

  // --- exact reconstruction; counts broadcast in-wave via shfl.
  // C layout: row = quad*4 + r, col = n*16 + lc; col 30 = (n=1, lc=14).
  const int cnt_src = quad * 16 + 14;
  float vals[3][2][4];
  #pragma unroll
  for (int mt = 0; mt < 3; ++mt)
    #pragma unroll
    for (int r = 0; r < 4; ++r) {
      const int cnt = __shfl(accl[mt][1][r], cnt_src, 64);
      #pragma unroll
      for (int n = 0; n < 2; ++n) {
        const int raw = (acch[mt][n][r] << 8) + accl[mt][n][r] + 32896 * cnt;
        float v = (float)raw * 1.52587890625e-5f;   // / 65536
        if (n == 1 && lc == 14) v = (float)accl[mt][n][r];   // counts column raw
        vals[mt][n][r] = v;
      }
    }

  // k-half combine: q2==1 stores to red, q2==0 adds and writes ws
  if (q2 == 1) {
    float* S = &red[mq * 48 * 33];
    #pragma unroll
    for (int mt = 0; mt < 3; ++mt)
      #pragma unroll
      for (int n = 0; n < 2; ++n)
        #pragma unroll
        for (int r = 0; r < 4; ++r)
          S[(mt * 16 + quad * 4 + r) * 33 + n * 16 + lc] = vals[mt][n][r];
  }
  __syncthreads();
  if (q2 == 0) {
    float* S = &red[mq * 48 * 33];
    float* W = ws + (long)bid * 6144;
    #pragma unroll
    for (int mt = 0; mt < 3; ++mt)
      #pragma unroll
      for (int n = 0; n < 2; ++n)
        #pragma unroll
        for (int r = 0; r < 4; ++r) {
          const float v = vals[mt][n][r] + S[(mt * 16 + quad * 4 + r) * 33 + n * 16 + lc];
          W[(mq * 48 + mt * 16 + quad * 4 + r) * 32 + n * 16 + lc] = v;
        }
  }
}

// Epilogue: one block per (bc, p). Stage 8x576 partials coalesced into LDS,
// 120 threads (s,a) compute entropy, 30 threads reduce over s.
__global__ __launch_bounds__(256)
void mi_ent(const float* __restrict__ ws, float* __restrict__ out) {
  __shared__ float tbl[8 * 576];
  __shared__ float red[4][32];
  const int bc = blockIdx.x / FP_;
  const int p  = blockIdx.x - bc * FP_;
  const int tid = threadIdx.x;

  #pragma unroll
  for (int it = 0; it < 18; ++it) {
    const int i = it * 256 + tid;
    const int sub = i / 576, r = i - sub * 576;   // sub = s*2 + half
    tbl[i] = ws[(long)(bc * 8 + sub) * 6144 + p * 576 + r];
  }
  __syncthreads();

  if (tid < 120) {
    const int s = tid / FA_;
    const int a = tid - s * FA_;
    const float* t0 = &tbl[(2 * s) * 576];
    const float* t1 = &tbl[(2 * s + 1) * 576];
    float m[K_];
    float tot = 0.0f;
    #pragma unroll
    for (int k = 0; k < K_; ++k) {
      const float cnt = t0[k * 32 + 30] + t1[k * 32 + 30];
      const float sv  = t0[k * 32 + a]  + t1[k * 32 + a];
      const float mk  = sv / (cnt + 1e-9f);
      m[k] = mk;
      tot += mk;
    }
    const float denom = tot + 1e-9f;
    float ent = 0.0f;
    #pragma unroll
    for (int k = 0; k < K_; ++k) {
      const float pr = m[k] / denom;
      ent += pr * logf(pr + 1e-9f);
    }
    const float L = logf(18.0f);
    red[s][a] = (L + ent) / L;
  }
  __syncthreads();
  if (tid < FA_)
    out[(bc * FP_ + p) * FA_ + tid] =
        0.25f * (red[0][tid] + red[1][tid] + red[2][tid] + red[3][tid]);
}

extern "C" void kernel_launch(void* const* d_in, const int* in_sizes, int n_in,
                              void* d_out, int out_size, void* d_ws, size_t ws_size,
                              hipStream_t stream) {
  const float* pha = (const float*)d_in[0];
  const float* amp = (const float*)d_in[1];
  float* out = (float*)d_out;
  float* ws  = (float*)d_ws;   // 512 * 6144 f32 = 12.6 MB partials

  hipLaunchKernelGGL(mi_main, dim3(512), dim3(NT_), LDS_TOTAL, stream, pha, amp, ws);
  hipLaunchKernelGGL(mi_ent, dim3(64 * FP_), dim3(256), 0, stream, ws, out);
}